// Round 11
// baseline (115.722 us; speedup 1.0000x reference)
//
#include <hip/hip_runtime.h>

typedef unsigned int u32;
typedef unsigned short u16;
typedef __attribute__((ext_vector_type(8))) __bf16 bf16x8;
typedef __attribute__((ext_vector_type(4))) float f32x4;

#define B_SZ 2048
#define IN_SZ 1024
#define K_SZ 128
#define E_SZ 64
#define TWOE 128
static const size_t OUT_EMB = (size_t)B_SZ * K_SZ * E_SZ;  // 16,777,216

__device__ __forceinline__ u16 f2bf(float f) {
    u32 u = __builtin_bit_cast(u32, f);
    u32 r = u + 0x7fffu + ((u >> 16) & 1u);
    return (u16)(r >> 16);
}

__device__ __forceinline__ void async16(const void* g, void* l) {
    __builtin_amdgcn_global_load_lds((const __attribute__((address_space(1))) u32*)g,
                                     (__attribute__((address_space(3))) u32*)l, 16, 0, 0);
}

// ---------------- conversion kernels ----------------
__global__ void __launch_bounds__(256) cvt_x(const float* __restrict__ in, u16* __restrict__ outp, int n4) {
    int i = blockIdx.x * blockDim.x + threadIdx.x;
    if (i < n4) {
        float4 v = ((const float4*)in)[i];
        u32 lo = (u32)f2bf(v.x) | ((u32)f2bf(v.y) << 16);
        u32 hi = (u32)f2bf(v.z) | ((u32)f2bf(v.w) << 16);
        ((uint2*)outp)[i] = make_uint2(lo, hi);
    }
}

// W[k][i][o] f32 -> Wt[k][o][i] bf16.  grid (16 i-blocks, 128 k), 256 thr
__global__ void __launch_bounds__(256) cvt_w(const float* __restrict__ W, u16* __restrict__ wt) {
    __shared__ u16 tr[128][72];
    const int k = blockIdx.y, i0 = blockIdx.x * 64;
    const float* src = W + (size_t)k * IN_SZ * TWOE + (size_t)i0 * TWOE;
#pragma unroll
    for (int r = 0; r < 8; ++r) {
        int idx = r * 256 + threadIdx.x;
        int i = idx >> 5;
        int o = (idx & 31) * 4;
        float4 v = ((const float4*)src)[idx];
        tr[o + 0][i] = f2bf(v.x);
        tr[o + 1][i] = f2bf(v.y);
        tr[o + 2][i] = f2bf(v.z);
        tr[o + 3][i] = f2bf(v.w);
    }
    __syncthreads();
    const int o = threadIdx.x >> 1, h = threadIdx.x & 1;
    u16* dst = wt + ((size_t)(k * TWOE + o) * IN_SZ) + i0 + h * 32;
#pragma unroll
    for (int s = 0; s < 4; ++s) {
        uint4 v = *(const uint4*)&tr[o][h * 32 + s * 8];
        ((uint4*)dst)[s] = v;
    }
}

// pw[k][b] -> out_pred[b][k] transpose, 16 blocks x 256 thr
__global__ void __launch_bounds__(256) cvt_pred(const float* __restrict__ pw, float* __restrict__ out) {
    __shared__ float t[128][132];
    const int b0 = blockIdx.x * 128;
    const int tid = threadIdx.x;
#pragma unroll
    for (int i = 0; i < 16; ++i) {
        int idx = i * 256 + tid;
        int kk = idx >> 5, c4 = (idx & 31) * 4;
        float4 v = *(const float4*)(pw + (size_t)kk * B_SZ + b0 + c4);
        t[kk][c4 + 0] = v.x; t[kk][c4 + 1] = v.y; t[kk][c4 + 2] = v.z; t[kk][c4 + 3] = v.w;
    }
    __syncthreads();
#pragma unroll
    for (int i = 0; i < 16; ++i) {
        int idx = i * 256 + tid;
        int bl = idx >> 5, k4 = (idx & 31) * 4;
        float4 v = make_float4(t[k4 + 0][bl], t[k4 + 1][bl], t[k4 + 2][bl], t[k4 + 3][bl]);
        *(float4*)(out + OUT_EMB + (size_t)(b0 + bl) * K_SZ + k4) = v;
    }
}

// ---------------- fused GEMM + epilogue: anti-phased K-tile loop ----------------
// Tile 256(b) x 256(two k's x 128 o) x K=1024; 16 K-tiles of 64 (2 kh panels of 32).
// 512 threads = 8 waves (2M x 4N), per-wave 128x64, acc[8][4].
// LDS: A[2dbuf][2kh][256][32] bf16 (64 KB) + B same (64 KB).
// Per K-tile: stage all 4 panels of t+1 FIRST (DMA hides under compute), then
// waves 0-3 compute kh0->kh1 while waves 4-7 compute kh1->kh0 (waves w and w+4
// share a SIMD -> anti-phased: one reads LDS while the other runs its MFMA
// cluster; R8-R10's barrier-per-phase aligned them and left ~55% stall).
// ONE vmcnt(0) + ONE barrier per K-tile (16 sync points total).
// grid: 512 blocks (8 brow x 64 kpair), XCD-chunked (8 kpair per XCD).
__global__ void __launch_bounds__(512, 2) fused_main(
    const u16* __restrict__ xb,   // [B][IN] bf16
    const u16* __restrict__ wt,   // [K][2E][IN] bf16
    const float* __restrict__ bias, const float* __restrict__ wpv,
    const float* __restrict__ bpp, float* __restrict__ out,
    float* __restrict__ pw) {
    __shared__ union {
        u16 stage[65536];   // A: (d*2+kh)*8192 .. ; B: 32768 + (d*2+kh)*8192
        struct { float pl[2][256][2]; float ex[2][256][66]; } epi;
    } sm;
    char* smb = (char*)&sm;

    const int tid = threadIdx.x;
    const int l = tid & 63, w = tid >> 6;    // lane, wave 0..7
    const int wm = w >> 2, wn = w & 3;       // 2M x 4N
    const int hi = l >> 4, lo16 = l & 15;
    const int q = l >> 2;                    // staging row-in-16
    const int swz = (l & 3) ^ ((l >> 3) & 3);

    // XCD-chunked mapping: xcd owns 8 kpairs; brow varies fastest
    const int id = blockIdx.x;
    const int xcd = id & 7, j = id >> 3;     // j 0..63
    const int kp = (xcd << 3) | (j >> 3);    // 0..63
    const int brow = (j & 7) << 8;           // 0..1792

    // staging source bases (pre-swizzled slot); LDS dest linear
    const u16* abase = xb + (size_t)(brow + w * 16 + q) * IN_SZ + swz * 8;
    const u16* bbase = wt + ((size_t)kp * 256 + w * 16 + q) * IN_SZ + swz * 8;

    // ds_read swizzled slot offset (bytes)
    const int xsl = (hi ^ ((lo16 >> 1) & 3)) << 4;

    f32x4 acc[8][4] = {};

    // stage one K-half panel (256 rows x 32 k = 16 KB): 2 loads/thread
    auto SA = [&](int d, int kh, int t) {
        u16* dst = (u16*)&sm + (d * 2 + kh) * 8192 + w * 512;
        const u16* src = abase + t * 64 + kh * 32;
        async16(src, dst);
        async16(src + (size_t)128 * IN_SZ, dst + 4096);
    };
    auto SB = [&](int d, int kh, int t) {
        u16* dst = (u16*)&sm + 32768 + (d * 2 + kh) * 8192 + w * 512;
        const u16* src = bbase + t * 64 + kh * 32;
        async16(src, dst);
        async16(src + (size_t)128 * IN_SZ, dst + 4096);
    };

    // one kh-panel compute: 12 ds_read_b128 + 32 MFMA; no sync inside
    auto PHN = [&](int d, int kh) {
        const char* ra = smb + (d * 2 + kh) * 16384;
        const char* rb = smb + 65536 + (d * 2 + kh) * 16384;
        bf16x8 af[8], bfr[4];
#pragma unroll
        for (int n = 0; n < 4; ++n)
            bfr[n] = *(const bf16x8*)(rb + (wn * 64 + n * 16 + lo16) * 64 + xsl);
#pragma unroll
        for (int mm = 0; mm < 8; ++mm)
            af[mm] = *(const bf16x8*)(ra + (wm * 128 + mm * 16 + lo16) * 64 + xsl);
        __builtin_amdgcn_s_setprio(1);
#pragma unroll
        for (int mm = 0; mm < 8; ++mm)
#pragma unroll
            for (int n = 0; n < 4; ++n)
                acc[mm][n] = __builtin_amdgcn_mfma_f32_16x16x32_bf16(
                    af[mm], bfr[n], acc[mm][n], 0, 0, 0);
        __builtin_amdgcn_s_setprio(0);
    };

    const int khf = wm;   // waves 0-3 start kh0; waves 4-7 start kh1 (anti-phase)

    // prologue: stage tile 0 (both kh panels), drain, barrier
    SA(0, 0, 0); SB(0, 0, 0); SA(0, 1, 0); SB(0, 1, 0);
    asm volatile("s_waitcnt vmcnt(0)" ::: "memory");
    __builtin_amdgcn_s_barrier();

#pragma unroll 1
    for (int t = 0; t < 16; ++t) {
        const int d = t & 1, dn = d ^ 1;
        if (t < 15) {
            SA(dn, 0, t + 1); SB(dn, 0, t + 1);
            SA(dn, 1, t + 1); SB(dn, 1, t + 1);
            asm volatile("" ::: "memory");   // keep stage issue ahead of compute
        }
        PHN(d, khf);
        PHN(d, khf ^ 1);
        // t+1's 8 DMAs were in flight across the whole tile -> drain is ~free
        asm volatile("s_waitcnt vmcnt(0)" ::: "memory");
        __builtin_amdgcn_s_barrier();
    }

    // ---- epilogue ----
    const int ksel = wn >> 1, oh = wn & 1;   // k within pair; pos/neg half
    const int kglob = kp * 2 + ksel;
    const float bp_val = *bpp;
    float bvals[4], wvals[4];
#pragma unroll
    for (int n = 0; n < 4; ++n) {
        const int o = oh * 64 + n * 16 + lo16;
        bvals[n] = bias[kglob * TWOE + o];
        wvals[n] = wpv[o];
    }
    float p[8][4];
#pragma unroll
    for (int m = 0; m < 8; ++m)
#pragma unroll
        for (int jj = 0; jj < 4; ++jj) {
            float s = 0.f;
#pragma unroll
            for (int n = 0; n < 4; ++n) {
                float v = acc[m][n][jj] + bvals[n];
                v = v > 0.f ? v : 0.01f * v;
                acc[m][n][jj] = v;          // ctx kept in acc
                s += v * wvals[n];
            }
            s += __shfl_xor(s, 1);
            s += __shfl_xor(s, 2);
            s += __shfl_xor(s, 4);
            s += __shfl_xor(s, 8);
            p[m][jj] = s;
        }
    if (lo16 == 0) {
#pragma unroll
        for (int m = 0; m < 8; ++m)
#pragma unroll
            for (int jj = 0; jj < 4; ++jj)
                sm.epi.pl[ksel][wm * 128 + m * 16 + hi * 4 + jj][oh] = p[m][jj];
    }
    __builtin_amdgcn_s_barrier();
#pragma unroll
    for (int m = 0; m < 8; ++m)
#pragma unroll
        for (int jj = 0; jj < 4; ++jj) {
            const int rg = wm * 128 + m * 16 + hi * 4 + jj;
            const float z = sm.epi.pl[ksel][rg][0] + sm.epi.pl[ksel][rg][1] + bp_val;
            p[m][jj] = 1.f / (1.f + __expf(-z));
        }
    if (oh == 0 && lo16 == 0) {
        if (pw) {
#pragma unroll
            for (int m = 0; m < 8; ++m) {
                float4 v = make_float4(p[m][0], p[m][1], p[m][2], p[m][3]);
                *(float4*)(pw + (size_t)kglob * B_SZ + brow + wm * 128 + m * 16 + hi * 4) = v;
            }
        } else {
#pragma unroll
            for (int m = 0; m < 8; ++m)
#pragma unroll
                for (int jj = 0; jj < 4; ++jj) {
                    const int b = brow + wm * 128 + m * 16 + hi * 4 + jj;
                    out[OUT_EMB + (size_t)b * K_SZ + kglob] = p[m][jj];
                }
        }
    }
    // c_emb: neg waves (oh==1) ship (1-p)*ctx_neg via LDS; pos waves combine+store
    if (oh == 1) {
#pragma unroll
        for (int m = 0; m < 8; ++m)
#pragma unroll
            for (int n = 0; n < 4; ++n)
#pragma unroll
                for (int jj = 0; jj < 4; ++jj)
                    sm.epi.ex[ksel][wm * 128 + m * 16 + hi * 4 + jj][n * 16 + lo16] =
                        (1.f - p[m][jj]) * acc[m][n][jj];
    }
    __builtin_amdgcn_s_barrier();
    if (oh == 0) {
#pragma unroll
        for (int m = 0; m < 8; ++m)
#pragma unroll
            for (int n = 0; n < 4; ++n)
#pragma unroll
                for (int jj = 0; jj < 4; ++jj) {
                    const int rl = wm * 128 + m * 16 + hi * 4 + jj;
                    const int b = brow + rl;
                    const int e = n * 16 + lo16;
                    out[((size_t)b * K_SZ + kglob) * E_SZ + e] =
                        p[m][jj] * acc[m][n][jj] + sm.epi.ex[ksel][rl][e];
                }
    }
}

// ---------------- no-ws fallback (correctness insurance) ----------------
__global__ void __launch_bounds__(128) fallback_kernel(
    const float* __restrict__ x, const float* __restrict__ W,
    const float* __restrict__ bias, const float* __restrict__ wpv,
    const float* __restrict__ bpp, float* __restrict__ out) {
    const int k = blockIdx.y;
    const int b0 = blockIdx.x * 8;
    const int o = threadIdx.x;
    __shared__ float xs[8][1024];
    __shared__ float red[2];
    __shared__ float exch[64];
    for (int idx = threadIdx.x; idx < 8 * 1024; idx += 128)
        xs[idx >> 10][idx & 1023] = x[(size_t)(b0 + (idx >> 10)) * IN_SZ + (idx & 1023)];
    __syncthreads();
    float a[8] = {};
    for (int i = 0; i < 1024; ++i) {
        float wv = W[((size_t)k * IN_SZ + i) * TWOE + o];
#pragma unroll
        for (int bb = 0; bb < 8; ++bb) a[bb] += xs[bb][i] * wv;
    }
    const float bo = bias[k * TWOE + o], wo = wpv[o], bpv = *bpp;
    for (int bb = 0; bb < 8; ++bb) {
        float c = a[bb] + bo;
        c = c > 0.f ? c : 0.01f * c;
        float s = c * wo;
        for (int off = 1; off < 64; off <<= 1) s += __shfl_xor(s, off);
        if ((threadIdx.x & 63) == 0) red[threadIdx.x >> 6] = s;
        __syncthreads();
        float p = 1.f / (1.f + expf(-(red[0] + red[1] + bpv)));
        if (o >= 64) exch[o - 64] = (1.f - p) * c;
        __syncthreads();
        if (o < 64) out[((size_t)(b0 + bb) * K_SZ + k) * E_SZ + o] = p * c + exch[o];
        if (o == 0) out[OUT_EMB + (size_t)(b0 + bb) * K_SZ + k] = p;
        __syncthreads();
    }
}

extern "C" void kernel_launch(void* const* d_in, const int* in_sizes, int n_in,
                              void* d_out, int out_size, void* d_ws, size_t ws_size,
                              hipStream_t stream) {
    const float* x = (const float*)d_in[0];
    const float* W = (const float*)d_in[1];
    const float* bias = (const float*)d_in[2];
    const float* wp = (const float*)d_in[3];
    const float* bp = (const float*)d_in[4];
    float* out = (float*)d_out;

    const size_t X_ELEMS = (size_t)B_SZ * IN_SZ;
    const size_t WT_ELEMS = (size_t)K_SZ * TWOE * IN_SZ;
    const size_t PW_ELEMS = (size_t)K_SZ * B_SZ;
    const size_t NEED_BASE = (X_ELEMS + WT_ELEMS) * sizeof(u16);
    const size_t NEED_FULL = NEED_BASE + PW_ELEMS * sizeof(float);

    if (ws_size >= NEED_BASE) {
        u16* xb = (u16*)d_ws;
        u16* wt = xb + X_ELEMS;
        float* pw = (ws_size >= NEED_FULL) ? (float*)(wt + WT_ELEMS) : nullptr;
        int n4 = (int)(X_ELEMS / 4);
        cvt_x<<<dim3((n4 + 255) / 256), 256, 0, stream>>>(x, xb, n4);
        cvt_w<<<dim3(16, 128), 256, 0, stream>>>(W, wt);
        fused_main<<<dim3(512), 512, 0, stream>>>(xb, wt, bias, wp, bp, out, pw);
        if (pw) cvt_pred<<<dim3(16), 256, 0, stream>>>(pw, out);
    } else {
        fallback_kernel<<<dim3(B_SZ / 8, K_SZ), 128, 0, stream>>>(x, W, bias, wp, bp, out);
    }
}

// Round 12
// 109.693 us; speedup vs baseline: 1.0550x; 1.0550x over previous
//
#include <hip/hip_runtime.h>

typedef unsigned int u32;
typedef unsigned short u16;
typedef __attribute__((ext_vector_type(8))) __bf16 bf16x8;
typedef __attribute__((ext_vector_type(4))) float f32x4;

#define B_SZ 2048
#define IN_SZ 1024
#define K_SZ 128
#define E_SZ 64
#define TWOE 128
static const size_t OUT_EMB = (size_t)B_SZ * K_SZ * E_SZ;  // 16,777,216

__device__ __forceinline__ u16 f2bf(float f) {
    u32 u = __builtin_bit_cast(u32, f);
    u32 r = u + 0x7fffu + ((u >> 16) & 1u);
    return (u16)(r >> 16);
}

__device__ __forceinline__ void async16(const void* g, void* l) {
    __builtin_amdgcn_global_load_lds((const __attribute__((address_space(1))) u32*)g,
                                     (__attribute__((address_space(3))) u32*)l, 16, 0, 0);
}

// ---------------- conversion kernels ----------------
__global__ void __launch_bounds__(256) cvt_x(const float* __restrict__ in, u16* __restrict__ outp, int n4) {
    int i = blockIdx.x * blockDim.x + threadIdx.x;
    if (i < n4) {
        float4 v = ((const float4*)in)[i];
        u32 lo = (u32)f2bf(v.x) | ((u32)f2bf(v.y) << 16);
        u32 hi = (u32)f2bf(v.z) | ((u32)f2bf(v.w) << 16);
        ((uint2*)outp)[i] = make_uint2(lo, hi);
    }
}

// W[k][i][o] f32 -> Wt[k][o][i] bf16.  grid (16 i-blocks, 128 k), 256 thr
__global__ void __launch_bounds__(256) cvt_w(const float* __restrict__ W, u16* __restrict__ wt) {
    __shared__ u16 tr[128][72];
    const int k = blockIdx.y, i0 = blockIdx.x * 64;
    const float* src = W + (size_t)k * IN_SZ * TWOE + (size_t)i0 * TWOE;
#pragma unroll
    for (int r = 0; r < 8; ++r) {
        int idx = r * 256 + threadIdx.x;
        int i = idx >> 5;
        int o = (idx & 31) * 4;
        float4 v = ((const float4*)src)[idx];
        tr[o + 0][i] = f2bf(v.x);
        tr[o + 1][i] = f2bf(v.y);
        tr[o + 2][i] = f2bf(v.z);
        tr[o + 3][i] = f2bf(v.w);
    }
    __syncthreads();
    const int o = threadIdx.x >> 1, h = threadIdx.x & 1;
    u16* dst = wt + ((size_t)(k * TWOE + o) * IN_SZ) + i0 + h * 32;
#pragma unroll
    for (int s = 0; s < 4; ++s) {
        uint4 v = *(const uint4*)&tr[o][h * 32 + s * 8];
        ((uint4*)dst)[s] = v;
    }
}

// pw[k][b] -> out_pred[b][k] transpose, 16 blocks x 256 thr
__global__ void __launch_bounds__(256) cvt_pred(const float* __restrict__ pw, float* __restrict__ out) {
    __shared__ float t[128][132];
    const int b0 = blockIdx.x * 128;
    const int tid = threadIdx.x;
#pragma unroll
    for (int i = 0; i < 16; ++i) {
        int idx = i * 256 + tid;
        int kk = idx >> 5, c4 = (idx & 31) * 4;
        float4 v = *(const float4*)(pw + (size_t)kk * B_SZ + b0 + c4);
        t[kk][c4 + 0] = v.x; t[kk][c4 + 1] = v.y; t[kk][c4 + 2] = v.z; t[kk][c4 + 3] = v.w;
    }
    __syncthreads();
#pragma unroll
    for (int i = 0; i < 16; ++i) {
        int idx = i * 256 + tid;
        int bl = idx >> 5, k4 = (idx & 31) * 4;
        float4 v = make_float4(t[k4 + 0][bl], t[k4 + 1][bl], t[k4 + 2][bl], t[k4 + 3][bl]);
        *(float4*)(out + OUT_EMB + (size_t)(b0 + bl) * K_SZ + k4) = v;
    }
}

// ---------------- fused GEMM + epilogue: swapped-operand C[o][b] ----------------
// K-loop identical to R10 (best measured: 85.2us). OPERANDS SWAPPED: A=Wt rows
// (256 = two k's x 128 o), B=x rows (256 b). C[o][b]: row(reg)=o, col(lane&15)=b.
// => per-thread regs hold 4 CONSECUTIVE e (hi*4+jj), and pos(m<4)/neg(m>=4) pair
// within the SAME thread: sigmoid-mix fully in-register, float4 c_emb stores from
// all 512 threads, no epilogue LDS exchange / barriers.
// LDS: pure stage 128 KB: A(Wt)[2d][2kh][256][32] + B(x) same.
// grid: 512 blocks (8 brow x 64 kpair), XCD-chunked (8 kpair per XCD).
__global__ void __launch_bounds__(512, 2) fused_main(
    const u16* __restrict__ xb,   // [B][IN] bf16
    const u16* __restrict__ wt,   // [K][2E][IN] bf16
    const float* __restrict__ bias, const float* __restrict__ wpv,
    const float* __restrict__ bpp, float* __restrict__ out,
    float* __restrict__ pw) {
    __shared__ u16 smst[65536];   // A(Wt): (d*2+kh)*8192 ; B(x): 32768 + (d*2+kh)*8192
    char* smb = (char*)&smst[0];

    const int tid = threadIdx.x;
    const int l = tid & 63, w = tid >> 6;    // lane, wave 0..7
    const int wm = w >> 2, wn = w & 3;       // wm = k-within-pair; wn = b quadrant
    const int hi = l >> 4, lo16 = l & 15;
    const int q = l >> 2;                    // staging row-in-16
    const int swz = (l & 3) ^ ((l >> 3) & 3);

    // XCD-chunked mapping: xcd owns 8 kpairs; brow varies fastest
    const int id = blockIdx.x;
    const int xcd = id & 7, j = id >> 3;     // j 0..63
    const int kp = (xcd << 3) | (j >> 3);    // 0..63
    const int brow = (j & 7) << 8;           // 0..1792

    // staging source bases (pre-swizzled slot); LDS dest linear
    const u16* abase = wt + ((size_t)kp * 256 + w * 16 + q) * IN_SZ + swz * 8;  // A = Wt
    const u16* bbase = xb + (size_t)(brow + w * 16 + q) * IN_SZ + swz * 8;      // B = x

    // ds_read swizzled slot offset (bytes)
    const int xsl = (hi ^ ((lo16 >> 1) & 3)) << 4;

    f32x4 acc[8][4] = {};

    // stage one K-half panel (256 rows x 32 k = 16 KB): 2 loads/thread each
    auto SA = [&](int d, int kh, int t) {
        u16* dst = &smst[0] + (d * 2 + kh) * 8192 + w * 512;
        const u16* src = abase + t * 64 + kh * 32;
        async16(src, dst);
        async16(src + (size_t)128 * IN_SZ, dst + 4096);
    };
    auto SB = [&](int d, int kh, int t) {
        u16* dst = &smst[0] + 32768 + (d * 2 + kh) * 8192 + w * 512;
        const u16* src = bbase + t * 64 + kh * 32;
        async16(src, dst);
        async16(src + (size_t)128 * IN_SZ, dst + 4096);
    };

    // one kh-panel compute: 12 ds_read_b128 + 32 MFMA; no sync inside
    auto PHN = [&](int d, int kh) {
        const char* ra = smb + (d * 2 + kh) * 16384;
        const char* rb = smb + 65536 + (d * 2 + kh) * 16384;
        bf16x8 af[8], bfr[4];
#pragma unroll
        for (int n = 0; n < 4; ++n)
            bfr[n] = *(const bf16x8*)(rb + (wn * 64 + n * 16 + lo16) * 64 + xsl);
#pragma unroll
        for (int mm = 0; mm < 8; ++mm)
            af[mm] = *(const bf16x8*)(ra + (wm * 128 + mm * 16 + lo16) * 64 + xsl);
        __builtin_amdgcn_s_setprio(1);
#pragma unroll
        for (int mm = 0; mm < 8; ++mm)
#pragma unroll
            for (int n = 0; n < 4; ++n)
                acc[mm][n] = __builtin_amdgcn_mfma_f32_16x16x32_bf16(
                    af[mm], bfr[n], acc[mm][n], 0, 0, 0);
        __builtin_amdgcn_s_setprio(0);
    };

    // prologue: stage tile 0 (both kh panels), drain, barrier
    SA(0, 0, 0); SB(0, 0, 0); SA(0, 1, 0); SB(0, 1, 0);
    asm volatile("s_waitcnt vmcnt(0)" ::: "memory");
    __builtin_amdgcn_s_barrier();

#pragma unroll 1
    for (int t = 0; t < 16; ++t) {
        const int d = t & 1, dn = d ^ 1;
        if (t < 15) {
            SA(dn, 0, t + 1); SB(dn, 0, t + 1);
            SA(dn, 1, t + 1); SB(dn, 1, t + 1);
            asm volatile("" ::: "memory");   // keep stage issue ahead of compute
        }
        PHN(d, 0);
        PHN(d, 1);
        // t+1's 8 DMAs were in flight across the whole tile -> drain is ~free
        asm volatile("s_waitcnt vmcnt(0)" ::: "memory");
        __builtin_amdgcn_s_barrier();
    }

    // ---- epilogue (pure-register: no LDS, no barriers) ----
    const int kglob = kp * 2 + wm;
    const float bp_val = *bpp;
    // per-m float4 bias/wp at e0 = m*16 + hi*4  (e = m*16 + hi*4 + jj)
    float4 b4[8], w4[8];
#pragma unroll
    for (int m = 0; m < 8; ++m) {
        b4[m] = *(const float4*)(bias + kglob * TWOE + m * 16 + hi * 4);
        w4[m] = *(const float4*)(wpv + m * 16 + hi * 4);
    }
    // ctx = leaky(acc + bias); dot over e; reduce across hi (lanes ^16, ^32)
    float pn[4];
#pragma unroll
    for (int n = 0; n < 4; ++n) {
        float s = 0.f;
#pragma unroll
        for (int m = 0; m < 8; ++m) {
            f32x4 v = acc[m][n];
            float t0 = v[0] + b4[m].x; t0 = t0 > 0.f ? t0 : 0.01f * t0;
            float t1 = v[1] + b4[m].y; t1 = t1 > 0.f ? t1 : 0.01f * t1;
            float t2 = v[2] + b4[m].z; t2 = t2 > 0.f ? t2 : 0.01f * t2;
            float t3 = v[3] + b4[m].w; t3 = t3 > 0.f ? t3 : 0.01f * t3;
            v[0] = t0; v[1] = t1; v[2] = t2; v[3] = t3;
            acc[m][n] = v;                    // ctx kept in acc
            s += t0 * w4[m].x + t1 * w4[m].y + t2 * w4[m].z + t3 * w4[m].w;
        }
        s += __shfl_xor(s, 16);
        s += __shfl_xor(s, 32);
        pn[n] = 1.f / (1.f + __expf(-(s + bp_val)));
    }
    // c_pred: lanes hi==0 store 4 values each (coalesced 64B groups via pw)
    if (hi == 0) {
        if (pw) {
#pragma unroll
            for (int n = 0; n < 4; ++n)
                pw[(size_t)kglob * B_SZ + brow + wn * 64 + n * 16 + lo16] = pn[n];
        } else {
#pragma unroll
            for (int n = 0; n < 4; ++n)
                out[OUT_EMB + (size_t)(brow + wn * 64 + n * 16 + lo16) * K_SZ + kglob] = pn[n];
        }
    }
    // c_emb: float4 per (n, mp): e0 = mp*16 + hi*4; pos=acc[mp], neg=acc[mp+4]
#pragma unroll
    for (int n = 0; n < 4; ++n) {
        const size_t bb = (size_t)(brow + wn * 64 + n * 16 + lo16);
        float* op = out + (bb * K_SZ + kglob) * E_SZ + hi * 4;
        const float pv = pn[n], qv = 1.f - pn[n];
#pragma unroll
        for (int mp = 0; mp < 4; ++mp) {
            f32x4 cp = acc[mp][n], cn = acc[mp + 4][n];
            f32x4 r;
            r[0] = pv * cp[0] + qv * cn[0];
            r[1] = pv * cp[1] + qv * cn[1];
            r[2] = pv * cp[2] + qv * cn[2];
            r[3] = pv * cp[3] + qv * cn[3];
            *(f32x4*)(op + mp * 16) = r;
        }
    }
}

// ---------------- no-ws fallback (correctness insurance) ----------------
__global__ void __launch_bounds__(128) fallback_kernel(
    const float* __restrict__ x, const float* __restrict__ W,
    const float* __restrict__ bias, const float* __restrict__ wpv,
    const float* __restrict__ bpp, float* __restrict__ out) {
    const int k = blockIdx.y;
    const int b0 = blockIdx.x * 8;
    const int o = threadIdx.x;
    __shared__ float xs[8][1024];
    __shared__ float red[2];
    __shared__ float exch[64];
    for (int idx = threadIdx.x; idx < 8 * 1024; idx += 128)
        xs[idx >> 10][idx & 1023] = x[(size_t)(b0 + (idx >> 10)) * IN_SZ + (idx & 1023)];
    __syncthreads();
    float a[8] = {};
    for (int i = 0; i < 1024; ++i) {
        float wv = W[((size_t)k * IN_SZ + i) * TWOE + o];
#pragma unroll
        for (int bb = 0; bb < 8; ++bb) a[bb] += xs[bb][i] * wv;
    }
    const float bo = bias[k * TWOE + o], wo = wpv[o], bpv = *bpp;
    for (int bb = 0; bb < 8; ++bb) {
        float c = a[bb] + bo;
        c = c > 0.f ? c : 0.01f * c;
        float s = c * wo;
        for (int off = 1; off < 64; off <<= 1) s += __shfl_xor(s, off);
        if ((threadIdx.x & 63) == 0) red[threadIdx.x >> 6] = s;
        __syncthreads();
        float p = 1.f / (1.f + expf(-(red[0] + red[1] + bpv)));
        if (o >= 64) exch[o - 64] = (1.f - p) * c;
        __syncthreads();
        if (o < 64) out[((size_t)(b0 + bb) * K_SZ + k) * E_SZ + o] = p * c + exch[o];
        if (o == 0) out[OUT_EMB + (size_t)(b0 + bb) * K_SZ + k] = p;
        __syncthreads();
    }
}

extern "C" void kernel_launch(void* const* d_in, const int* in_sizes, int n_in,
                              void* d_out, int out_size, void* d_ws, size_t ws_size,
                              hipStream_t stream) {
    const float* x = (const float*)d_in[0];
    const float* W = (const float*)d_in[1];
    const float* bias = (const float*)d_in[2];
    const float* wp = (const float*)d_in[3];
    const float* bp = (const float*)d_in[4];
    float* out = (float*)d_out;

    const size_t X_ELEMS = (size_t)B_SZ * IN_SZ;
    const size_t WT_ELEMS = (size_t)K_SZ * TWOE * IN_SZ;
    const size_t PW_ELEMS = (size_t)K_SZ * B_SZ;
    const size_t NEED_BASE = (X_ELEMS + WT_ELEMS) * sizeof(u16);
    const size_t NEED_FULL = NEED_BASE + PW_ELEMS * sizeof(float);

    if (ws_size >= NEED_BASE) {
        u16* xb = (u16*)d_ws;
        u16* wt = xb + X_ELEMS;
        float* pw = (ws_size >= NEED_FULL) ? (float*)(wt + WT_ELEMS) : nullptr;
        int n4 = (int)(X_ELEMS / 4);
        cvt_x<<<dim3((n4 + 255) / 256), 256, 0, stream>>>(x, xb, n4);
        cvt_w<<<dim3(16, 128), 256, 0, stream>>>(W, wt);
        fused_main<<<dim3(512), 512, 0, stream>>>(xb, wt, bias, wp, bp, out, pw);
        if (pw) cvt_pred<<<dim3(16), 256, 0, stream>>>(pw, out);
    } else {
        fallback_kernel<<<dim3(B_SZ / 8, K_SZ), 128, 0, stream>>>(x, W, bias, wp, bp, out);
    }
}

// Round 13
// 108.376 us; speedup vs baseline: 1.0678x; 1.0121x over previous
//
#include <hip/hip_runtime.h>

typedef unsigned int u32;
typedef unsigned short u16;
typedef __attribute__((ext_vector_type(8))) __bf16 bf16x8;
typedef __attribute__((ext_vector_type(4))) float f32x4;

#define B_SZ 2048
#define IN_SZ 1024
#define K_SZ 128
#define E_SZ 64
#define TWOE 128
static const size_t OUT_EMB = (size_t)B_SZ * K_SZ * E_SZ;  // 16,777,216

__device__ __forceinline__ u16 f2bf(float f) {
    u32 u = __builtin_bit_cast(u32, f);
    u32 r = u + 0x7fffu + ((u >> 16) & 1u);
    return (u16)(r >> 16);
}

__device__ __forceinline__ void async16(const void* g, void* l) {
    __builtin_amdgcn_global_load_lds((const __attribute__((address_space(1))) u32*)g,
                                     (__attribute__((address_space(3))) u32*)l, 16, 0, 0);
}

// ---------------- conversion kernels ----------------
__global__ void __launch_bounds__(256) cvt_x(const float* __restrict__ in, u16* __restrict__ outp, int n4) {
    int i = blockIdx.x * blockDim.x + threadIdx.x;
    if (i < n4) {
        float4 v = ((const float4*)in)[i];
        u32 lo = (u32)f2bf(v.x) | ((u32)f2bf(v.y) << 16);
        u32 hi = (u32)f2bf(v.z) | ((u32)f2bf(v.w) << 16);
        ((uint2*)outp)[i] = make_uint2(lo, hi);
    }
}

// W[k][i][o] f32 -> Wt[k][o][i] bf16.  grid (16 i-blocks, 128 k), 256 thr
__global__ void __launch_bounds__(256) cvt_w(const float* __restrict__ W, u16* __restrict__ wt) {
    __shared__ u16 tr[128][72];
    const int k = blockIdx.y, i0 = blockIdx.x * 64;
    const float* src = W + (size_t)k * IN_SZ * TWOE + (size_t)i0 * TWOE;
#pragma unroll
    for (int r = 0; r < 8; ++r) {
        int idx = r * 256 + threadIdx.x;
        int i = idx >> 5;
        int o = (idx & 31) * 4;
        float4 v = ((const float4*)src)[idx];
        tr[o + 0][i] = f2bf(v.x);
        tr[o + 1][i] = f2bf(v.y);
        tr[o + 2][i] = f2bf(v.z);
        tr[o + 3][i] = f2bf(v.w);
    }
    __syncthreads();
    const int o = threadIdx.x >> 1, h = threadIdx.x & 1;
    u16* dst = wt + ((size_t)(k * TWOE + o) * IN_SZ) + i0 + h * 32;
#pragma unroll
    for (int s = 0; s < 4; ++s) {
        uint4 v = *(const uint4*)&tr[o][h * 32 + s * 8];
        ((uint4*)dst)[s] = v;
    }
}

// pw[k][b] -> out_pred[b][k] transpose, 16 blocks x 256 thr
__global__ void __launch_bounds__(256) cvt_pred(const float* __restrict__ pw, float* __restrict__ out) {
    __shared__ float t[128][132];
    const int b0 = blockIdx.x * 128;
    const int tid = threadIdx.x;
#pragma unroll
    for (int i = 0; i < 16; ++i) {
        int idx = i * 256 + tid;
        int kk = idx >> 5, c4 = (idx & 31) * 4;
        float4 v = *(const float4*)(pw + (size_t)kk * B_SZ + b0 + c4);
        t[kk][c4 + 0] = v.x; t[kk][c4 + 1] = v.y; t[kk][c4 + 2] = v.z; t[kk][c4 + 3] = v.w;
    }
    __syncthreads();
#pragma unroll
    for (int i = 0; i < 16; ++i) {
        int idx = i * 256 + tid;
        int bl = idx >> 5, k4 = (idx & 31) * 4;
        float4 v = make_float4(t[k4 + 0][bl], t[k4 + 1][bl], t[k4 + 2][bl], t[k4 + 3][bl]);
        *(float4*)(out + OUT_EMB + (size_t)(b0 + bl) * K_SZ + k4) = v;
    }
}

// ---------------- fused GEMM + epilogue: 2-block/CU double-buffer ----------------
// R12's swapped-operand C[o][b] kernel with ONE change: stage buffer shrunk from
// 4 panels (128 KB, 1 block/CU) to 2-panel double-buffer (64 KB -> 2 blocks/CU,
// 16 waves/CU, 4/SIMD). Co-resident blocks' barriers are independent: when one
// block drains at its barrier, the other's waves own the SIMD (m114 overlap).
// 32 K-panels of 32; per panel: stage t+1 (4 DMA/thr), 12 ds_read_b128, 32 MFMA,
// vmcnt(0)+barrier (2 buffers require full drain).
// A=Wt rows (256 = two k x 128 o), B=x rows (256 b). C: row=o, col=b -> pos/neg
// in same thread, register-only epilogue, zero bank conflicts (R12 measured).
// grid: 512 blocks (8 brow x 64 kpair), XCD-chunked (8 kpair per XCD).
__global__ void __launch_bounds__(512, 2) fused_main(
    const u16* __restrict__ xb,   // [B][IN] bf16
    const u16* __restrict__ wt,   // [K][2E][IN] bf16
    const float* __restrict__ bias, const float* __restrict__ wpv,
    const float* __restrict__ bpp, float* __restrict__ out,
    float* __restrict__ pw) {
    __shared__ u16 smst[32768];   // A(Wt): d*8192 ; B(x): 16384 + d*8192  (u16 idx)
    char* smb = (char*)&smst[0];

    const int tid = threadIdx.x;
    const int l = tid & 63, w = tid >> 6;    // lane, wave 0..7
    const int wm = w >> 2, wn = w & 3;       // wm = k-within-pair; wn = b quadrant
    const int hi = l >> 4, lo16 = l & 15;
    const int q = l >> 2;                    // staging row-in-16
    const int swz = (l & 3) ^ ((l >> 3) & 3);

    // XCD-chunked mapping: xcd owns 8 kpairs; brow varies fastest
    const int id = blockIdx.x;
    const int xcd = id & 7, j = id >> 3;     // j 0..63
    const int kp = (xcd << 3) | (j >> 3);    // 0..63
    const int brow = (j & 7) << 8;           // 0..1792

    // staging source bases (pre-swizzled slot); LDS dest linear
    const u16* abase = wt + ((size_t)kp * 256 + w * 16 + q) * IN_SZ + swz * 8;  // A = Wt
    const u16* bbase = xb + (size_t)(brow + w * 16 + q) * IN_SZ + swz * 8;      // B = x

    // ds_read swizzled slot offset (bytes)
    const int xsl = (hi ^ ((lo16 >> 1) & 3)) << 4;

    f32x4 acc[8][4] = {};

    // stage one K-panel (256 rows x 32 k = 16 KB each for A and B): 2+2 loads/thread
    auto SA = [&](int d, int tp) {
        u16* dst = &smst[0] + d * 8192 + w * 512;
        const u16* src = abase + tp * 32;
        async16(src, dst);
        async16(src + (size_t)128 * IN_SZ, dst + 4096);
    };
    auto SB = [&](int d, int tp) {
        u16* dst = &smst[0] + 16384 + d * 8192 + w * 512;
        const u16* src = bbase + tp * 32;
        async16(src, dst);
        async16(src + (size_t)128 * IN_SZ, dst + 4096);
    };

    // one K-panel compute: 12 ds_read_b128 + 32 MFMA; no sync inside
    auto PHN = [&](int d) {
        const char* ra = smb + d * 16384;
        const char* rb = smb + 32768 + d * 16384;
        bf16x8 af[8], bfr[4];
#pragma unroll
        for (int n = 0; n < 4; ++n)
            bfr[n] = *(const bf16x8*)(rb + (wn * 64 + n * 16 + lo16) * 64 + xsl);
#pragma unroll
        for (int mm = 0; mm < 8; ++mm)
            af[mm] = *(const bf16x8*)(ra + (wm * 128 + mm * 16 + lo16) * 64 + xsl);
        __builtin_amdgcn_s_setprio(1);
#pragma unroll
        for (int mm = 0; mm < 8; ++mm)
#pragma unroll
            for (int n = 0; n < 4; ++n)
                acc[mm][n] = __builtin_amdgcn_mfma_f32_16x16x32_bf16(
                    af[mm], bfr[n], acc[mm][n], 0, 0, 0);
        __builtin_amdgcn_s_setprio(0);
    };

    // prologue: stage panel 0 into buf 0, drain, barrier
    SA(0, 0); SB(0, 0);
    asm volatile("s_waitcnt vmcnt(0)" ::: "memory");
    __builtin_amdgcn_s_barrier();

#pragma unroll 1
    for (int t = 0; t < 32; ++t) {
        const int d = t & 1;
        if (t < 31) {
            SA(d ^ 1, t + 1); SB(d ^ 1, t + 1);
            asm volatile("" ::: "memory");   // keep stage issue ahead of compute
        }
        PHN(d);
        // t+1's 4 DMAs were in flight across the compute -> drain is mostly hidden
        asm volatile("s_waitcnt vmcnt(0)" ::: "memory");
        __builtin_amdgcn_s_barrier();
    }

    // ---- epilogue (pure-register: no LDS, no barriers) ----
    const int kglob = kp * 2 + wm;
    const float bp_val = *bpp;
    // per-m float4 bias/wp at e0 = m*16 + hi*4  (e = m*16 + hi*4 + jj)
    float4 b4[8], w4[8];
#pragma unroll
    for (int m = 0; m < 8; ++m) {
        b4[m] = *(const float4*)(bias + kglob * TWOE + m * 16 + hi * 4);
        w4[m] = *(const float4*)(wpv + m * 16 + hi * 4);
    }
    // ctx = leaky(acc + bias); dot over e; reduce across hi (lanes ^16, ^32)
    float pn[4];
#pragma unroll
    for (int n = 0; n < 4; ++n) {
        float s = 0.f;
#pragma unroll
        for (int m = 0; m < 8; ++m) {
            f32x4 v = acc[m][n];
            float t0 = v[0] + b4[m].x; t0 = t0 > 0.f ? t0 : 0.01f * t0;
            float t1 = v[1] + b4[m].y; t1 = t1 > 0.f ? t1 : 0.01f * t1;
            float t2 = v[2] + b4[m].z; t2 = t2 > 0.f ? t2 : 0.01f * t2;
            float t3 = v[3] + b4[m].w; t3 = t3 > 0.f ? t3 : 0.01f * t3;
            v[0] = t0; v[1] = t1; v[2] = t2; v[3] = t3;
            acc[m][n] = v;                    // ctx kept in acc
            s += t0 * w4[m].x + t1 * w4[m].y + t2 * w4[m].z + t3 * w4[m].w;
        }
        s += __shfl_xor(s, 16);
        s += __shfl_xor(s, 32);
        pn[n] = 1.f / (1.f + __expf(-(s + bp_val)));
    }
    // c_pred: lanes hi==0 store 4 values each (coalesced via pw)
    if (hi == 0) {
        if (pw) {
#pragma unroll
            for (int n = 0; n < 4; ++n)
                pw[(size_t)kglob * B_SZ + brow + wn * 64 + n * 16 + lo16] = pn[n];
        } else {
#pragma unroll
            for (int n = 0; n < 4; ++n)
                out[OUT_EMB + (size_t)(brow + wn * 64 + n * 16 + lo16) * K_SZ + kglob] = pn[n];
        }
    }
    // c_emb: float4 per (n, mp): e0 = mp*16 + hi*4; pos=acc[mp], neg=acc[mp+4]
#pragma unroll
    for (int n = 0; n < 4; ++n) {
        const size_t bb = (size_t)(brow + wn * 64 + n * 16 + lo16);
        float* op = out + (bb * K_SZ + kglob) * E_SZ + hi * 4;
        const float pv = pn[n], qv = 1.f - pn[n];
#pragma unroll
        for (int mp = 0; mp < 4; ++mp) {
            f32x4 cp = acc[mp][n], cn = acc[mp + 4][n];
            f32x4 r;
            r[0] = pv * cp[0] + qv * cn[0];
            r[1] = pv * cp[1] + qv * cn[1];
            r[2] = pv * cp[2] + qv * cn[2];
            r[3] = pv * cp[3] + qv * cn[3];
            *(f32x4*)(op + mp * 16) = r;
        }
    }
}

// ---------------- no-ws fallback (correctness insurance) ----------------
__global__ void __launch_bounds__(128) fallback_kernel(
    const float* __restrict__ x, const float* __restrict__ W,
    const float* __restrict__ bias, const float* __restrict__ wpv,
    const float* __restrict__ bpp, float* __restrict__ out) {
    const int k = blockIdx.y;
    const int b0 = blockIdx.x * 8;
    const int o = threadIdx.x;
    __shared__ float xs[8][1024];
    __shared__ float red[2];
    __shared__ float exch[64];
    for (int idx = threadIdx.x; idx < 8 * 1024; idx += 128)
        xs[idx >> 10][idx & 1023] = x[(size_t)(b0 + (idx >> 10)) * IN_SZ + (idx & 1023)];
    __syncthreads();
    float a[8] = {};
    for (int i = 0; i < 1024; ++i) {
        float wv = W[((size_t)k * IN_SZ + i) * TWOE + o];
#pragma unroll
        for (int bb = 0; bb < 8; ++bb) a[bb] += xs[bb][i] * wv;
    }
    const float bo = bias[k * TWOE + o], wo = wpv[o], bpv = *bpp;
    for (int bb = 0; bb < 8; ++bb) {
        float c = a[bb] + bo;
        c = c > 0.f ? c : 0.01f * c;
        float s = c * wo;
        for (int off = 1; off < 64; off <<= 1) s += __shfl_xor(s, off);
        if ((threadIdx.x & 63) == 0) red[threadIdx.x >> 6] = s;
        __syncthreads();
        float p = 1.f / (1.f + expf(-(red[0] + red[1] + bpv)));
        if (o >= 64) exch[o - 64] = (1.f - p) * c;
        __syncthreads();
        if (o < 64) out[((size_t)(b0 + bb) * K_SZ + k) * E_SZ + o] = p * c + exch[o];
        if (o == 0) out[OUT_EMB + (size_t)(b0 + bb) * K_SZ + k] = p;
        __syncthreads();
    }
}

extern "C" void kernel_launch(void* const* d_in, const int* in_sizes, int n_in,
                              void* d_out, int out_size, void* d_ws, size_t ws_size,
                              hipStream_t stream) {
    const float* x = (const float*)d_in[0];
    const float* W = (const float*)d_in[1];
    const float* bias = (const float*)d_in[2];
    const float* wp = (const float*)d_in[3];
    const float* bp = (const float*)d_in[4];
    float* out = (float*)d_out;

    const size_t X_ELEMS = (size_t)B_SZ * IN_SZ;
    const size_t WT_ELEMS = (size_t)K_SZ * TWOE * IN_SZ;
    const size_t PW_ELEMS = (size_t)K_SZ * B_SZ;
    const size_t NEED_BASE = (X_ELEMS + WT_ELEMS) * sizeof(u16);
    const size_t NEED_FULL = NEED_BASE + PW_ELEMS * sizeof(float);

    if (ws_size >= NEED_BASE) {
        u16* xb = (u16*)d_ws;
        u16* wt = xb + X_ELEMS;
        float* pw = (ws_size >= NEED_FULL) ? (float*)(wt + WT_ELEMS) : nullptr;
        int n4 = (int)(X_ELEMS / 4);
        cvt_x<<<dim3((n4 + 255) / 256), 256, 0, stream>>>(x, xb, n4);
        cvt_w<<<dim3(16, 128), 256, 0, stream>>>(W, wt);
        fused_main<<<dim3(512), 512, 0, stream>>>(xb, wt, bias, wp, bp, out, pw);
        if (pw) cvt_pred<<<dim3(16), 256, 0, stream>>>(pw, out);
    } else {
        fallback_kernel<<<dim3(B_SZ / 8, K_SZ), 128, 0, stream>>>(x, W, bias, wp, bp, out);
    }
}

// Round 14
// 108.087 us; speedup vs baseline: 1.0706x; 1.0027x over previous
//
#include <hip/hip_runtime.h>

typedef unsigned int u32;
typedef unsigned short u16;
typedef __attribute__((ext_vector_type(8))) __bf16 bf16x8;
typedef __attribute__((ext_vector_type(4))) float f32x4;

#define B_SZ 2048
#define IN_SZ 1024
#define K_SZ 128
#define E_SZ 64
#define TWOE 128
static const size_t OUT_EMB = (size_t)B_SZ * K_SZ * E_SZ;  // 16,777,216

__device__ __forceinline__ u16 f2bf(float f) {
    u32 u = __builtin_bit_cast(u32, f);
    u32 r = u + 0x7fffu + ((u >> 16) & 1u);
    return (u16)(r >> 16);
}

__device__ __forceinline__ void async16(const void* g, void* l) {
    __builtin_amdgcn_global_load_lds((const __attribute__((address_space(1))) u32*)g,
                                     (__attribute__((address_space(3))) u32*)l, 16, 0, 0);
}

// ---------------- conversion kernels ----------------
// cvt_xw: y<128 -> W[k][i][o] f32 -> Wt[k][o][i] bf16 (k=y, i0=x*64);
//         y>=128 -> x f32 -> bf16 chunk ((y-128)*16+x of 128 chunks).
__global__ void __launch_bounds__(256) cvt_xw(const float* __restrict__ W, u16* __restrict__ wt,
                                              const float* __restrict__ x, u16* __restrict__ xb) {
    const int tid = threadIdx.x;
    if (blockIdx.y < 128) {
        __shared__ u16 tr[128][72];
        const int k = blockIdx.y, i0 = blockIdx.x * 64;
        const float* src = W + (size_t)k * IN_SZ * TWOE + (size_t)i0 * TWOE;
#pragma unroll
        for (int r = 0; r < 8; ++r) {
            int idx = r * 256 + tid;
            int i = idx >> 5;
            int o = (idx & 31) * 4;
            float4 v = ((const float4*)src)[idx];
            tr[o + 0][i] = f2bf(v.x);
            tr[o + 1][i] = f2bf(v.y);
            tr[o + 2][i] = f2bf(v.z);
            tr[o + 3][i] = f2bf(v.w);
        }
        __syncthreads();
        const int o = tid >> 1, h = tid & 1;
        u16* dst = wt + ((size_t)(k * TWOE + o) * IN_SZ) + i0 + h * 32;
#pragma unroll
        for (int s = 0; s < 4; ++s) {
            uint4 v = *(const uint4*)&tr[o][h * 32 + s * 8];
            ((uint4*)dst)[s] = v;
        }
    } else {
        const int chunk = (blockIdx.y - 128) * 16 + blockIdx.x;   // 0..127
        const int base = chunk * 4096;                            // float4 units
#pragma unroll
        for (int s = 0; s < 16; ++s) {
            int i = base + s * 256 + tid;
            float4 v = ((const float4*)x)[i];
            u32 lo = (u32)f2bf(v.x) | ((u32)f2bf(v.y) << 16);
            u32 hi = (u32)f2bf(v.z) | ((u32)f2bf(v.w) << 16);
            ((uint2*)xb)[i] = make_uint2(lo, hi);
        }
    }
}

// pw[k][b] -> out_pred[b][k] transpose, 16 blocks x 256 thr
__global__ void __launch_bounds__(256) cvt_pred(const float* __restrict__ pw, float* __restrict__ out) {
    __shared__ float t[128][132];
    const int b0 = blockIdx.x * 128;
    const int tid = threadIdx.x;
#pragma unroll
    for (int i = 0; i < 16; ++i) {
        int idx = i * 256 + tid;
        int kk = idx >> 5, c4 = (idx & 31) * 4;
        float4 v = *(const float4*)(pw + (size_t)kk * B_SZ + b0 + c4);
        t[kk][c4 + 0] = v.x; t[kk][c4 + 1] = v.y; t[kk][c4 + 2] = v.z; t[kk][c4 + 3] = v.w;
    }
    __syncthreads();
#pragma unroll
    for (int i = 0; i < 16; ++i) {
        int idx = i * 256 + tid;
        int bl = idx >> 5, k4 = (idx & 31) * 4;
        float4 v = make_float4(t[k4 + 0][bl], t[k4 + 1][bl], t[k4 + 2][bl], t[k4 + 3][bl]);
        *(float4*)(out + OUT_EMB + (size_t)(b0 + bl) * K_SZ + k4) = v;
    }
}

// ---------------- fused GEMM + epilogue: depth-2 prefetch, 2 blocks/CU ----------------
// R13 geometry unchanged (256x256 tile, 8 waves, 64 KB dbuf, swapped operands
// A=Wt/B=x, C[o][b], register epilogue, 0 bank conflicts). ONE loop change:
// per panel {ds_read(buf d) -> lgkmcnt(0) -> barrier -> stage(t+2 -> buf d) ->
// MFMA -> vmcnt(4) -> barrier}. Buffer d is dead once all waves' reads retire,
// so t+2 stages into it: prefetch depth 2 panels (~1400 cyc) with only 2 buffers.
// End-of-panel vmcnt(4) retires loads issued 2 panels ago -> drain stall gone
// (R13 drained same-panel DMAs: ~200 cyc exposed per panel).
// grid: 512 blocks (8 brow x 64 kpair), XCD-chunked (8 kpair per XCD).
__global__ void __launch_bounds__(512, 2) fused_main(
    const u16* __restrict__ xb,   // [B][IN] bf16
    const u16* __restrict__ wt,   // [K][2E][IN] bf16
    const float* __restrict__ bias, const float* __restrict__ wpv,
    const float* __restrict__ bpp, float* __restrict__ out,
    float* __restrict__ pw) {
    __shared__ u16 smst[32768];   // A(Wt): d*8192 ; B(x): 16384 + d*8192  (u16 idx)
    char* smb = (char*)&smst[0];

    const int tid = threadIdx.x;
    const int l = tid & 63, w = tid >> 6;    // lane, wave 0..7
    const int wm = w >> 2, wn = w & 3;       // wm = k-within-pair; wn = b quadrant
    const int hi = l >> 4, lo16 = l & 15;    // hi 0..3 (C/D row group)
    const int q = l >> 2;                    // staging row-in-16
    const int swz = (l & 3) ^ ((l >> 3) & 3);

    // XCD-chunked mapping: xcd owns 8 kpairs; brow varies fastest
    const int id = blockIdx.x;
    const int xcd = id & 7, j = id >> 3;     // j 0..63
    const int kp = (xcd << 3) | (j >> 3);    // 0..63
    const int brow = (j & 7) << 8;           // 0..1792

    // staging source bases (pre-swizzled slot); LDS dest linear
    const u16* abase = wt + ((size_t)kp * 256 + w * 16 + q) * IN_SZ + swz * 8;  // A = Wt
    const u16* bbase = xb + (size_t)(brow + w * 16 + q) * IN_SZ + swz * 8;      // B = x

    // ds_read swizzled slot offset (bytes)
    const int xsl = (hi ^ ((lo16 >> 1) & 3)) << 4;

    f32x4 acc[8][4] = {};

    // stage one K-panel (256 rows x 32 k = 16 KB each for A and B): 2+2 loads/thread
    auto SA = [&](int d, int tp) {
        u16* dst = &smst[0] + d * 8192 + w * 512;
        const u16* src = abase + tp * 32;
        async16(src, dst);
        async16(src + (size_t)128 * IN_SZ, dst + 4096);
    };
    auto SB = [&](int d, int tp) {
        u16* dst = &smst[0] + 16384 + d * 8192 + w * 512;
        const u16* src = bbase + tp * 32;
        async16(src, dst);
        async16(src + (size_t)128 * IN_SZ, dst + 4096);
    };

    // prologue: stage panel 0 and 1; wait panel 0 (vmcnt(4) leaves 1's in flight)
    SA(0, 0); SB(0, 0);
    SA(1, 1); SB(1, 1);
    asm volatile("s_waitcnt vmcnt(4)" ::: "memory");
    __builtin_amdgcn_s_barrier();

#pragma unroll 1
    for (int t = 0; t < 32; ++t) {
        const int d = t & 1;
        const char* ra = smb + d * 16384;
        const char* rb = smb + 32768 + d * 16384;
        bf16x8 af[8], bfr[4];
#pragma unroll
        for (int n = 0; n < 4; ++n)
            bfr[n] = *(const bf16x8*)(rb + (wn * 64 + n * 16 + lo16) * 64 + xsl);
#pragma unroll
        for (int mm = 0; mm < 8; ++mm)
            af[mm] = *(const bf16x8*)(ra + (wm * 128 + mm * 16 + lo16) * 64 + xsl);
        // buffer d dead once all waves' reads retired:
        asm volatile("s_waitcnt lgkmcnt(0)" ::: "memory");
        __builtin_amdgcn_s_barrier();
        __builtin_amdgcn_sched_barrier(0);
        if (t < 30) {                         // stage t+2 into the just-freed buffer
            SA(d, t + 2); SB(d, t + 2);
            asm volatile("" ::: "memory");
        }
        __builtin_amdgcn_s_setprio(1);
#pragma unroll
        for (int mm = 0; mm < 8; ++mm)
#pragma unroll
            for (int n = 0; n < 4; ++n)
                acc[mm][n] = __builtin_amdgcn_mfma_f32_16x16x32_bf16(
                    af[mm], bfr[n], acc[mm][n], 0, 0, 0);
        __builtin_amdgcn_s_setprio(0);
        // t+1's 4 loads (issued 2 iters ago) must retire; t+2's 4 stay in flight
        if (t < 30) asm volatile("s_waitcnt vmcnt(4)" ::: "memory");
        else        asm volatile("s_waitcnt vmcnt(0)" ::: "memory");
        __builtin_amdgcn_s_barrier();
    }

    // ---- epilogue (pure-register: no LDS, no barriers) ----
    const int kglob = kp * 2 + wm;
    const float bp_val = *bpp;
    float4 b4[8], w4[8];
#pragma unroll
    for (int m = 0; m < 8; ++m) {
        b4[m] = *(const float4*)(bias + kglob * TWOE + m * 16 + hi * 4);
        w4[m] = *(const float4*)(wpv + m * 16 + hi * 4);
    }
    float pn[4];
#pragma unroll
    for (int n = 0; n < 4; ++n) {
        float s = 0.f;
#pragma unroll
        for (int m = 0; m < 8; ++m) {
            f32x4 v = acc[m][n];
            float t0 = v[0] + b4[m].x; t0 = t0 > 0.f ? t0 : 0.01f * t0;
            float t1 = v[1] + b4[m].y; t1 = t1 > 0.f ? t1 : 0.01f * t1;
            float t2 = v[2] + b4[m].z; t2 = t2 > 0.f ? t2 : 0.01f * t2;
            float t3 = v[3] + b4[m].w; t3 = t3 > 0.f ? t3 : 0.01f * t3;
            v[0] = t0; v[1] = t1; v[2] = t2; v[3] = t3;
            acc[m][n] = v;                    // ctx kept in acc
            s += t0 * w4[m].x + t1 * w4[m].y + t2 * w4[m].z + t3 * w4[m].w;
        }
        s += __shfl_xor(s, 16);
        s += __shfl_xor(s, 32);
        pn[n] = 1.f / (1.f + __expf(-(s + bp_val)));
    }
    if (hi == 0) {
        if (pw) {
#pragma unroll
            for (int n = 0; n < 4; ++n)
                pw[(size_t)kglob * B_SZ + brow + wn * 64 + n * 16 + lo16] = pn[n];
        } else {
#pragma unroll
            for (int n = 0; n < 4; ++n)
                out[OUT_EMB + (size_t)(brow + wn * 64 + n * 16 + lo16) * K_SZ + kglob] = pn[n];
        }
    }
#pragma unroll
    for (int n = 0; n < 4; ++n) {
        const size_t bb = (size_t)(brow + wn * 64 + n * 16 + lo16);
        float* op = out + (bb * K_SZ + kglob) * E_SZ + hi * 4;
        const float pv = pn[n], qv = 1.f - pn[n];
#pragma unroll
        for (int mp = 0; mp < 4; ++mp) {
            f32x4 cp = acc[mp][n], cn = acc[mp + 4][n];
            f32x4 r;
            r[0] = pv * cp[0] + qv * cn[0];
            r[1] = pv * cp[1] + qv * cn[1];
            r[2] = pv * cp[2] + qv * cn[2];
            r[3] = pv * cp[3] + qv * cn[3];
            *(f32x4*)(op + mp * 16) = r;
        }
    }
}

// ---------------- no-ws fallback (correctness insurance) ----------------
__global__ void __launch_bounds__(128) fallback_kernel(
    const float* __restrict__ x, const float* __restrict__ W,
    const float* __restrict__ bias, const float* __restrict__ wpv,
    const float* __restrict__ bpp, float* __restrict__ out) {
    const int k = blockIdx.y;
    const int b0 = blockIdx.x * 8;
    const int o = threadIdx.x;
    __shared__ float xs[8][1024];
    __shared__ float red[2];
    __shared__ float exch[64];
    for (int idx = threadIdx.x; idx < 8 * 1024; idx += 128)
        xs[idx >> 10][idx & 1023] = x[(size_t)(b0 + (idx >> 10)) * IN_SZ + (idx & 1023)];
    __syncthreads();
    float a[8] = {};
    for (int i = 0; i < 1024; ++i) {
        float wv = W[((size_t)k * IN_SZ + i) * TWOE + o];
#pragma unroll
        for (int bb = 0; bb < 8; ++bb) a[bb] += xs[bb][i] * wv;
    }
    const float bo = bias[k * TWOE + o], wo = wpv[o], bpv = *bpp;
    for (int bb = 0; bb < 8; ++bb) {
        float c = a[bb] + bo;
        c = c > 0.f ? c : 0.01f * c;
        float s = c * wo;
        for (int off = 1; off < 64; off <<= 1) s += __shfl_xor(s, off);
        if ((threadIdx.x & 63) == 0) red[threadIdx.x >> 6] = s;
        __syncthreads();
        float p = 1.f / (1.f + expf(-(red[0] + red[1] + bpv)));
        if (o >= 64) exch[o - 64] = (1.f - p) * c;
        __syncthreads();
        if (o < 64) out[((size_t)(b0 + bb) * K_SZ + k) * E_SZ + o] = p * c + exch[o];
        if (o == 0) out[OUT_EMB + (size_t)(b0 + bb) * K_SZ + k] = p;
        __syncthreads();
    }
}

extern "C" void kernel_launch(void* const* d_in, const int* in_sizes, int n_in,
                              void* d_out, int out_size, void* d_ws, size_t ws_size,
                              hipStream_t stream) {
    const float* x = (const float*)d_in[0];
    const float* W = (const float*)d_in[1];
    const float* bias = (const float*)d_in[2];
    const float* wp = (const float*)d_in[3];
    const float* bp = (const float*)d_in[4];
    float* out = (float*)d_out;

    const size_t X_ELEMS = (size_t)B_SZ * IN_SZ;
    const size_t WT_ELEMS = (size_t)K_SZ * TWOE * IN_SZ;
    const size_t PW_ELEMS = (size_t)K_SZ * B_SZ;
    const size_t NEED_BASE = (X_ELEMS + WT_ELEMS) * sizeof(u16);
    const size_t NEED_FULL = NEED_BASE + PW_ELEMS * sizeof(float);

    if (ws_size >= NEED_BASE) {
        u16* xb = (u16*)d_ws;
        u16* wt = xb + X_ELEMS;
        float* pw = (ws_size >= NEED_FULL) ? (float*)(wt + WT_ELEMS) : nullptr;
        cvt_xw<<<dim3(16, 136), 256, 0, stream>>>(W, wt, x, xb);
        fused_main<<<dim3(512), 512, 0, stream>>>(xb, wt, bias, wp, bp, out, pw);
        if (pw) cvt_pred<<<dim3(16), 256, 0, stream>>>(pw, out);
    } else {
        fallback_kernel<<<dim3(B_SZ / 8, K_SZ), 128, 0, stream>>>(x, W, bias, wp, bp, out);
    }
}

// Round 15
// 103.441 us; speedup vs baseline: 1.1187x; 1.0449x over previous
//
#include <hip/hip_runtime.h>

typedef unsigned int u32;
typedef unsigned short u16;
typedef __attribute__((ext_vector_type(8))) __bf16 bf16x8;
typedef __attribute__((ext_vector_type(4))) float f32x4;

#define B_SZ 2048
#define IN_SZ 1024
#define K_SZ 128
#define E_SZ 64
#define TWOE 128
static const size_t OUT_EMB = (size_t)B_SZ * K_SZ * E_SZ;  // 16,777,216

__device__ __forceinline__ u16 f2bf(float f) {
    u32 u = __builtin_bit_cast(u32, f);
    u32 r = u + 0x7fffu + ((u >> 16) & 1u);
    return (u16)(r >> 16);
}

__device__ __forceinline__ void async16(const void* g, void* l) {
    __builtin_amdgcn_global_load_lds((const __attribute__((address_space(1))) u32*)g,
                                     (__attribute__((address_space(3))) u32*)l, 16, 0, 0);
}

// ---------------- conversion kernels ----------------
// cvt_xw: y<128 -> W[k][i][o] f32 -> Wt[k][o][i] bf16 (k=y, i0=x*64);
//         y>=128 -> x f32 -> bf16 chunk ((y-128)*16+x of 128 chunks).
__global__ void __launch_bounds__(256) cvt_xw(const float* __restrict__ W, u16* __restrict__ wt,
                                              const float* __restrict__ x, u16* __restrict__ xb) {
    const int tid = threadIdx.x;
    if (blockIdx.y < 128) {
        __shared__ u16 tr[128][72];
        const int k = blockIdx.y, i0 = blockIdx.x * 64;
        const float* src = W + (size_t)k * IN_SZ * TWOE + (size_t)i0 * TWOE;
#pragma unroll
        for (int r = 0; r < 8; ++r) {
            int idx = r * 256 + tid;
            int i = idx >> 5;
            int o = (idx & 31) * 4;
            float4 v = ((const float4*)src)[idx];
            tr[o + 0][i] = f2bf(v.x);
            tr[o + 1][i] = f2bf(v.y);
            tr[o + 2][i] = f2bf(v.z);
            tr[o + 3][i] = f2bf(v.w);
        }
        __syncthreads();
        const int o = tid >> 1, h = tid & 1;
        u16* dst = wt + ((size_t)(k * TWOE + o) * IN_SZ) + i0 + h * 32;
#pragma unroll
        for (int s = 0; s < 4; ++s) {
            uint4 v = *(const uint4*)&tr[o][h * 32 + s * 8];
            ((uint4*)dst)[s] = v;
        }
    } else {
        const int chunk = (blockIdx.y - 128) * 16 + blockIdx.x;   // 0..127
        const int base = chunk * 4096;                            // float4 units
#pragma unroll
        for (int s = 0; s < 16; ++s) {
            int i = base + s * 256 + tid;
            float4 v = ((const float4*)x)[i];
            u32 lo = (u32)f2bf(v.x) | ((u32)f2bf(v.y) << 16);
            u32 hi = (u32)f2bf(v.z) | ((u32)f2bf(v.w) << 16);
            ((uint2*)xb)[i] = make_uint2(lo, hi);
        }
    }
}

// pw[k][b] -> out_pred[b][k] transpose, 16 blocks x 256 thr
__global__ void __launch_bounds__(256) cvt_pred(const float* __restrict__ pw, float* __restrict__ out) {
    __shared__ float t[128][132];
    const int b0 = blockIdx.x * 128;
    const int tid = threadIdx.x;
#pragma unroll
    for (int i = 0; i < 16; ++i) {
        int idx = i * 256 + tid;
        int kk = idx >> 5, c4 = (idx & 31) * 4;
        float4 v = *(const float4*)(pw + (size_t)kk * B_SZ + b0 + c4);
        t[kk][c4 + 0] = v.x; t[kk][c4 + 1] = v.y; t[kk][c4 + 2] = v.z; t[kk][c4 + 3] = v.w;
    }
    __syncthreads();
#pragma unroll
    for (int i = 0; i < 16; ++i) {
        int idx = i * 256 + tid;
        int bl = idx >> 5, k4 = (idx & 31) * 4;
        float4 v = make_float4(t[k4 + 0][bl], t[k4 + 1][bl], t[k4 + 2][bl], t[k4 + 3][bl]);
        *(float4*)(out + OUT_EMB + (size_t)(b0 + bl) * K_SZ + k4) = v;
    }
}

// ---------------- fused GEMM + epilogue: R13 schedule (best measured: 79.2us) ----------------
// 256x256 tile, 8 waves, 64 KB double-buffer -> 2 blocks/CU (independent barriers
// give the m114 overlap). Swapped operands A=Wt/B=x, C[o][b]: pos/neg in same
// thread, register-only epilogue, zero bank conflicts.
// 32 K-panels of 32; per panel: stage t+1 (4 DMA/thr) FIRST, 12 ds_read_b128,
// 32 MFMA, vmcnt(0)+barrier. (R14's depth-2 variant with mid-panel barrier
// regressed 79->87: order-pinning defeated the compiler scheduler.)
// grid: 512 blocks (8 brow x 64 kpair), XCD-chunked (8 kpair per XCD).
__global__ void __launch_bounds__(512, 2) fused_main(
    const u16* __restrict__ xb,   // [B][IN] bf16
    const u16* __restrict__ wt,   // [K][2E][IN] bf16
    const float* __restrict__ bias, const float* __restrict__ wpv,
    const float* __restrict__ bpp, float* __restrict__ out,
    float* __restrict__ pw) {
    __shared__ u16 smst[32768];   // A(Wt): d*8192 ; B(x): 16384 + d*8192  (u16 idx)
    char* smb = (char*)&smst[0];

    const int tid = threadIdx.x;
    const int l = tid & 63, w = tid >> 6;    // lane, wave 0..7
    const int wm = w >> 2, wn = w & 3;       // wm = k-within-pair; wn = b quadrant
    const int hi = l >> 4, lo16 = l & 15;
    const int q = l >> 2;                    // staging row-in-16
    const int swz = (l & 3) ^ ((l >> 3) & 3);

    // XCD-chunked mapping: xcd owns 8 kpairs; brow varies fastest
    const int id = blockIdx.x;
    const int xcd = id & 7, j = id >> 3;     // j 0..63
    const int kp = (xcd << 3) | (j >> 3);    // 0..63
    const int brow = (j & 7) << 8;           // 0..1792

    // staging source bases (pre-swizzled slot); LDS dest linear
    const u16* abase = wt + ((size_t)kp * 256 + w * 16 + q) * IN_SZ + swz * 8;  // A = Wt
    const u16* bbase = xb + (size_t)(brow + w * 16 + q) * IN_SZ + swz * 8;      // B = x

    // ds_read swizzled slot offset (bytes)
    const int xsl = (hi ^ ((lo16 >> 1) & 3)) << 4;

    f32x4 acc[8][4] = {};

    // stage one K-panel (256 rows x 32 k = 16 KB each for A and B): 2+2 loads/thread
    auto SA = [&](int d, int tp) {
        u16* dst = &smst[0] + d * 8192 + w * 512;
        const u16* src = abase + tp * 32;
        async16(src, dst);
        async16(src + (size_t)128 * IN_SZ, dst + 4096);
    };
    auto SB = [&](int d, int tp) {
        u16* dst = &smst[0] + 16384 + d * 8192 + w * 512;
        const u16* src = bbase + tp * 32;
        async16(src, dst);
        async16(src + (size_t)128 * IN_SZ, dst + 4096);
    };

    // one K-panel compute: 12 ds_read_b128 + 32 MFMA; no sync inside
    auto PHN = [&](int d) {
        const char* ra = smb + d * 16384;
        const char* rb = smb + 32768 + d * 16384;
        bf16x8 af[8], bfr[4];
#pragma unroll
        for (int n = 0; n < 4; ++n)
            bfr[n] = *(const bf16x8*)(rb + (wn * 64 + n * 16 + lo16) * 64 + xsl);
#pragma unroll
        for (int mm = 0; mm < 8; ++mm)
            af[mm] = *(const bf16x8*)(ra + (wm * 128 + mm * 16 + lo16) * 64 + xsl);
        __builtin_amdgcn_s_setprio(1);
#pragma unroll
        for (int mm = 0; mm < 8; ++mm)
#pragma unroll
            for (int n = 0; n < 4; ++n)
                acc[mm][n] = __builtin_amdgcn_mfma_f32_16x16x32_bf16(
                    af[mm], bfr[n], acc[mm][n], 0, 0, 0);
        __builtin_amdgcn_s_setprio(0);
    };

    // prologue: stage panel 0 into buf 0, drain, barrier
    SA(0, 0); SB(0, 0);
    asm volatile("s_waitcnt vmcnt(0)" ::: "memory");
    __builtin_amdgcn_s_barrier();

#pragma unroll 1
    for (int t = 0; t < 32; ++t) {
        const int d = t & 1;
        if (t < 31) {
            SA(d ^ 1, t + 1); SB(d ^ 1, t + 1);
            asm volatile("" ::: "memory");   // keep stage issue ahead of compute
        }
        PHN(d);
        // t+1's 4 DMAs were in flight across the compute -> drain is mostly hidden
        asm volatile("s_waitcnt vmcnt(0)" ::: "memory");
        __builtin_amdgcn_s_barrier();
    }

    // ---- epilogue (pure-register: no LDS, no barriers) ----
    const int kglob = kp * 2 + wm;
    const float bp_val = *bpp;
    float4 b4[8], w4[8];
#pragma unroll
    for (int m = 0; m < 8; ++m) {
        b4[m] = *(const float4*)(bias + kglob * TWOE + m * 16 + hi * 4);
        w4[m] = *(const float4*)(wpv + m * 16 + hi * 4);
    }
    float pn[4];
#pragma unroll
    for (int n = 0; n < 4; ++n) {
        float s = 0.f;
#pragma unroll
        for (int m = 0; m < 8; ++m) {
            f32x4 v = acc[m][n];
            float t0 = v[0] + b4[m].x; t0 = t0 > 0.f ? t0 : 0.01f * t0;
            float t1 = v[1] + b4[m].y; t1 = t1 > 0.f ? t1 : 0.01f * t1;
            float t2 = v[2] + b4[m].z; t2 = t2 > 0.f ? t2 : 0.01f * t2;
            float t3 = v[3] + b4[m].w; t3 = t3 > 0.f ? t3 : 0.01f * t3;
            v[0] = t0; v[1] = t1; v[2] = t2; v[3] = t3;
            acc[m][n] = v;                    // ctx kept in acc
            s += t0 * w4[m].x + t1 * w4[m].y + t2 * w4[m].z + t3 * w4[m].w;
        }
        s += __shfl_xor(s, 16);
        s += __shfl_xor(s, 32);
        pn[n] = 1.f / (1.f + __expf(-(s + bp_val)));
    }
    if (hi == 0) {
        if (pw) {
#pragma unroll
            for (int n = 0; n < 4; ++n)
                pw[(size_t)kglob * B_SZ + brow + wn * 64 + n * 16 + lo16] = pn[n];
        } else {
#pragma unroll
            for (int n = 0; n < 4; ++n)
                out[OUT_EMB + (size_t)(brow + wn * 64 + n * 16 + lo16) * K_SZ + kglob] = pn[n];
        }
    }
#pragma unroll
    for (int n = 0; n < 4; ++n) {
        const size_t bb = (size_t)(brow + wn * 64 + n * 16 + lo16);
        float* op = out + (bb * K_SZ + kglob) * E_SZ + hi * 4;
        const float pv = pn[n], qv = 1.f - pn[n];
#pragma unroll
        for (int mp = 0; mp < 4; ++mp) {
            f32x4 cp = acc[mp][n], cn = acc[mp + 4][n];
            f32x4 r;
            r[0] = pv * cp[0] + qv * cn[0];
            r[1] = pv * cp[1] + qv * cn[1];
            r[2] = pv * cp[2] + qv * cn[2];
            r[3] = pv * cp[3] + qv * cn[3];
            *(f32x4*)(op + mp * 16) = r;
        }
    }
}

// ---------------- no-ws fallback (correctness insurance) ----------------
__global__ void __launch_bounds__(128) fallback_kernel(
    const float* __restrict__ x, const float* __restrict__ W,
    const float* __restrict__ bias, const float* __restrict__ wpv,
    const float* __restrict__ bpp, float* __restrict__ out) {
    const int k = blockIdx.y;
    const int b0 = blockIdx.x * 8;
    const int o = threadIdx.x;
    __shared__ float xs[8][1024];
    __shared__ float red[2];
    __shared__ float exch[64];
    for (int idx = threadIdx.x; idx < 8 * 1024; idx += 128)
        xs[idx >> 10][idx & 1023] = x[(size_t)(b0 + (idx >> 10)) * IN_SZ + (idx & 1023)];
    __syncthreads();
    float a[8] = {};
    for (int i = 0; i < 1024; ++i) {
        float wv = W[((size_t)k * IN_SZ + i) * TWOE + o];
#pragma unroll
        for (int bb = 0; bb < 8; ++bb) a[bb] += xs[bb][i] * wv;
    }
    const float bo = bias[k * TWOE + o], wo = wpv[o], bpv = *bpp;
    for (int bb = 0; bb < 8; ++bb) {
        float c = a[bb] + bo;
        c = c > 0.f ? c : 0.01f * c;
        float s = c * wo;
        for (int off = 1; off < 64; off <<= 1) s += __shfl_xor(s, off);
        if ((threadIdx.x & 63) == 0) red[threadIdx.x >> 6] = s;
        __syncthreads();
        float p = 1.f / (1.f + expf(-(red[0] + red[1] + bpv)));
        if (o >= 64) exch[o - 64] = (1.f - p) * c;
        __syncthreads();
        if (o < 64) out[((size_t)(b0 + bb) * K_SZ + k) * E_SZ + o] = p * c + exch[o];
        if (o == 0) out[OUT_EMB + (size_t)(b0 + bb) * K_SZ + k] = p;
        __syncthreads();
    }
}

extern "C" void kernel_launch(void* const* d_in, const int* in_sizes, int n_in,
                              void* d_out, int out_size, void* d_ws, size_t ws_size,
                              hipStream_t stream) {
    const float* x = (const float*)d_in[0];
    const float* W = (const float*)d_in[1];
    const float* bias = (const float*)d_in[2];
    const float* wp = (const float*)d_in[3];
    const float* bp = (const float*)d_in[4];
    float* out = (float*)d_out;

    const size_t X_ELEMS = (size_t)B_SZ * IN_SZ;
    const size_t WT_ELEMS = (size_t)K_SZ * TWOE * IN_SZ;
    const size_t PW_ELEMS = (size_t)K_SZ * B_SZ;
    const size_t NEED_BASE = (X_ELEMS + WT_ELEMS) * sizeof(u16);
    const size_t NEED_FULL = NEED_BASE + PW_ELEMS * sizeof(float);

    if (ws_size >= NEED_BASE) {
        u16* xb = (u16*)d_ws;
        u16* wt = xb + X_ELEMS;
        float* pw = (ws_size >= NEED_FULL) ? (float*)(wt + WT_ELEMS) : nullptr;
        cvt_xw<<<dim3(16, 136), 256, 0, stream>>>(W, wt, x, xb);
        fused_main<<<dim3(512), 512, 0, stream>>>(xb, wt, bias, wp, bp, out, pw);
        if (pw) cvt_pred<<<dim3(16), 256, 0, stream>>>(pw, out);
    } else {
        fallback_kernel<<<dim3(B_SZ / 8, K_SZ), 128, 0, stream>>>(x, W, bias, wp, bp, out);
    }
}